// Round 9
// baseline (265.946 us; speedup 1.0000x reference)
//
#include <hip/hip_runtime.h>
#include <stdint.h>

typedef unsigned short ushort_t;
typedef __attribute__((ext_vector_type(4))) unsigned int  u32x4;
typedef __attribute__((ext_vector_type(2))) unsigned int  u32x2;
typedef __attribute__((ext_vector_type(4))) float         f32x4;
typedef __attribute__((ext_vector_type(8))) __bf16        bf16x8;
typedef __attribute__((ext_vector_type(2))) __bf16        bf16x2;

__device__ __forceinline__ ushort_t f2bf(float f) {
    unsigned int u = __float_as_uint(f);
    u += 0x7fffu + ((u >> 16) & 1u);
    return (ushort_t)(u >> 16);
}
__device__ __forceinline__ unsigned int pack2bf(float a, float b) {
    return (unsigned int)f2bf(a) | ((unsigned int)f2bf(b) << 16);
}
#if __has_builtin(__builtin_amdgcn_cvt_pk_bf16_f32)
__device__ __forceinline__ unsigned int pack2bf_fast(float a, float b) {
    bf16x2 v = __builtin_amdgcn_cvt_pk_bf16_f32(a, b);
    return __builtin_bit_cast(unsigned int, v);
}
#else
__device__ __forceinline__ unsigned int pack2bf_fast(float a, float b) {
    return pack2bf(a, b);
}
#endif
__device__ __forceinline__ f32x4 mfma16(bf16x8 a, bf16x8 b, f32x4 c) {
    return __builtin_amdgcn_mfma_f32_16x16x32_bf16(a, b, c, 0, 0, 0);
}
__device__ __forceinline__ bf16x8 ldfrag(const ushort_t* p) {
    return __builtin_bit_cast(bf16x8, *(const u32x4*)p);
}

// async global->LDS 16B: LDS dest = wave-uniform base + lane*16 (linear);
// swizzle lives in the per-lane GLOBAL source address (guide m97/m173).
__device__ __forceinline__ void gld16(const ushort_t* g, ushort_t* l) {
    __builtin_amdgcn_global_load_lds(
        (const __attribute__((address_space(1))) void*)g,
        (__attribute__((address_space(3))) void*)l, 16, 0, 0);
}

// Raw workgroup barrier WITHOUT the vmcnt(0) drain __syncthreads emits.
__device__ __forceinline__ void wg_barrier() {
    asm volatile("s_waitcnt lgkmcnt(0)\n\ts_barrier" ::: "memory");
}

// 0.125 (1/sqrt(64)) * log2(e): folded into Q so softmax uses exp2
#define QSCALE 0.18033688011112042f

// ---------------------------------------------------------------------------
// prep: fused  xcast (blocks 0..4095) | Wqkv^T (4096..7167) | Wproj^T (rest)
// ---------------------------------------------------------------------------
__global__ __launch_bounds__(256) void prep(const float* __restrict__ X,
                                            ushort_t* __restrict__ Xb,
                                            const float* __restrict__ Wq,
                                            ushort_t* __restrict__ Wqt,
                                            const float* __restrict__ Wp,
                                            ushort_t* __restrict__ Wpt) {
    __shared__ float tile[32][33];
    const int tid = threadIdx.x;
    const int b   = blockIdx.x;
    if (b < 4096) {                      // x fp32 -> bf16, 8 elems/thread
        long i = ((long)b * 256 + tid) * 8;
        float4 a = *(const float4*)(X + i);
        float4 c = *(const float4*)(X + i + 4);
        u32x4 pk;
        pk.x = pack2bf(a.x, a.y); pk.y = pack2bf(a.z, a.w);
        pk.z = pack2bf(c.x, c.y); pk.w = pack2bf(c.z, c.w);
        *(u32x4*)(Xb + i) = pk;
        return;
    }
    const float* W; ushort_t* Wt; int N, bx, by;
    if (b < 7168) { int idx = b - 4096; W = Wq; Wt = Wqt; N = 3072; bx = idx % 96; by = idx / 96; }
    else          { int idx = b - 7168; W = Wp; Wt = Wpt; N = 1024; bx = idx & 31; by = idx >> 5; }
    const int tx = tid & 31, ty = tid >> 5;
    const int n0 = bx * 32, k0 = by * 32;
    for (int p = 0; p < 4; ++p)
        tile[ty + 8*p][tx] = W[(long)(k0 + ty + 8*p) * N + n0 + tx];
    __syncthreads();
    for (int p = 0; p < 4; ++p)
        Wt[(long)(n0 + ty + 8*p) * 1024 + k0 + tx] = f2bf(tile[tx][ty + 8*p]);
}

// ---------------------------------------------------------------------------
// GEMM1: qkv = xb @ Wt + b.  (round-2 proven pipeline: gld_lds staging,
// 3-buffer rotation, ONE barrier per 32-wide K-phase with counted
// s_waitcnt vmcnt(4); prefetch never drained in-loop. 48KB LDS.)
// ---------------------------------------------------------------------------
__global__ __launch_bounds__(256) void gemm_qkv(const ushort_t* __restrict__ Xb,
                                                const ushort_t* __restrict__ Wt,
                                                const float* __restrict__ bias,
                                                ushort_t* __restrict__ Qo,
                                                ushort_t* __restrict__ Ko,
                                                ushort_t* __restrict__ Vto) {
    __shared__ __align__(16) ushort_t smem[24576];

    const int tid  = threadIdx.x;
    const int g    = blockIdx.x;
    const int grp  = g / 192, rr = g % 192;
    const int m0   = (grp * 8 + (rr & 7)) * 128;
    const int n0   = (rr >> 3) * 128;
    const int lane = tid & 63, w = tid >> 6;
    const int quad = lane >> 4, l16 = lane & 15;
    const int wm = (w >> 1) * 64, wn = (w & 1) * 64;

    const int srow  = tid >> 2;
    const int slot  = tid & 3;
    const int oct   = slot ^ ((tid >> 3) & 3);          // global-side swizzle
    const int rslot = (quad ^ ((l16 >> 1) & 3)) * 8;    // frag-read swizzled slot
    const int wbase = (tid & 192) * 8;                  // wave-uniform LDS base

    const ushort_t* Ap = Xb + (long)(m0 + srow) * 1024 + oct * 8;
    const ushort_t* Bp = Wt + (long)(n0 + srow) * 1024 + oct * 8;

    f32x4 acc[4][4] = {};

    auto issue = [&](int pf, int ibuf) {
        int k = (pf < 32) ? (pf << 5) : 0;              // clamp: harmless junk
        gld16(Ap + k,         &smem[ibuf + wbase]);
        gld16(Ap + k + 65536, &smem[ibuf + wbase + 2048]);
        gld16(Bp + k,         &smem[ibuf + wbase + 4096]);
        gld16(Bp + k + 65536, &smem[ibuf + wbase + 6144]);
    };
    auto step = [&](int p, int rbuf, int ibuf) {
        asm volatile("s_waitcnt vmcnt(4)\n\ts_barrier" ::: "memory");
        issue(p + 2, ibuf);
        const ushort_t* As = smem + rbuf;
        const ushort_t* Bs = As + 4096;
        bf16x8 af[4], bfr[4];
        for (int i = 0; i < 4; ++i)
            af[i] = ldfrag(&As[(wm + 16*i + l16) * 32 + rslot]);
        for (int j = 0; j < 4; ++j)
            bfr[j] = ldfrag(&Bs[(wn + 16*j + l16) * 32 + rslot]);
        __builtin_amdgcn_s_setprio(1);
        for (int i = 0; i < 4; ++i)
            for (int j = 0; j < 4; ++j)
                acc[i][j] = mfma16(af[i], bfr[j], acc[i][j]);
        __builtin_amdgcn_s_setprio(0);
    };

    issue(0, 0);
    issue(1, 8192);
    for (int p = 0; p < 30; p += 3) {
        step(p,     0,     16384);
        step(p + 1, 8192,  0);
        step(p + 2, 16384, 8192);
    }
    step(30, 0,    16384);
    step(31, 8192, 0);

    float bj[4];
    for (int j = 0; j < 4; ++j) bj[j] = bias[n0 + wn + 16*j + l16];
    const int bb = m0 >> 11, t0m = m0 & 2047;
    asm volatile("s_waitcnt vmcnt(0)" ::: "memory");    // junk tail loads landed
    __syncthreads();                                    // smem reuse safe

    if (n0 < 2048) {
        // Q or K: transpose-in-LDS as [t_local][n_local], store 16B chunks
        ushort_t* dst = (n0 < 1024) ? Qo : Ko;
        const float scale = (n0 < 1024) ? QSCALE : 1.0f;
        const int nbase = (n0 < 1024) ? n0 : n0 - 1024;
        for (int i = 0; i < 4; ++i)
            for (int j = 0; j < 4; ++j) {
                int nl = wn + 16*j + l16;
                for (int r = 0; r < 4; ++r) {
                    int ml = wm + 16*i + quad*4 + r;
                    smem[ml * 136 + nl] = f2bf((acc[i][j][r] + bj[j]) * scale);
                }
            }
        __syncthreads();
        for (int c = 0; c < 8; ++c) {
            int chunk = tid + 256 * c;
            int row = chunk >> 4, nc = (chunk & 15) * 8;
            int n = nbase + nc;
            int hh = n >> 6, d = n & 63;
            *(u32x4*)&dst[((long)(bb*16 + hh) * 2048 + t0m + row) * 64 + d] =
                *(const u32x4*)&smem[row * 136 + nc];
        }
    } else {
        // V: transpose as [n_local][t_local], store [B,H,D,T] 16B chunks
        for (int i = 0; i < 4; ++i)
            for (int j = 0; j < 4; ++j) {
                int nl = wn + 16*j + l16;
                for (int r = 0; r < 4; ++r) {
                    int ml = wm + 16*i + quad*4 + r;
                    smem[nl * 136 + ml] = f2bf(acc[i][j][r] + bj[j]);
                }
            }
        __syncthreads();
        for (int c = 0; c < 8; ++c) {
            int chunk = tid + 256 * c;
            int row = chunk >> 4, mc = (chunk & 15) * 8;
            int n = n0 - 2048 + row;
            int hh = n >> 6, d = n & 63;
            *(u32x4*)&Vto[((long)(bb*16 + hh) * 64 + d) * 2048 + t0m + mc] =
                *(const u32x4*)&smem[row * 136 + mc];
        }
    }
}

// ---------------------------------------------------------------------------
// Causal flash attention. CHANGE vs R8: LDS 50KB -> 32KB => 4 blocks/CU
// (was 3). Phases are latency-bound (~2.7Kcyc vs ~500cyc issue work), so
// resident-wave TLP is the multiplier. How: (a) K and V single-buffered
// (2 barriers/tile instead of 1; register prefetch 1 tile ahead still covers
// ~900cyc HBM latency since a phase is ~2Kcyc); (b) Ps[128][72] pad ->
// XOR-swizzled [128][64] (elem = row*64 + (col ^ ((row&7)*8)); all P/Q cols
// are 4/8-aligned so the XOR permutes 8-elem blocks wholesale; write & read
// use the identical transform; ~2-way banks, same as the pad); (c) Q stages
// through the P region before the k-loop. Single K/V prefetch reg set also
// saves 16 VGPR. MFMA-computed l (R8) kept. No min-waves launch bound.
// ---------------------------------------------------------------------------
__global__ __launch_bounds__(256) void attn_kernel(const ushort_t* __restrict__ Q,
                                                   const ushort_t* __restrict__ K,
                                                   const ushort_t* __restrict__ Vt,
                                                   ushort_t* __restrict__ O) {
    __shared__ __align__(16) ushort_t Ks[64 * 64];     // single buffer, swizzled
    __shared__ __align__(16) ushort_t Vs[64 * 64];     // single buffer, swizzled
    __shared__ __align__(16) ushort_t Ps[128 * 64];    // Q staging then P (XOR swz)

    const int tid  = threadIdx.x;
    const int lane = tid & 63, w = tid >> 6, quad = lane >> 4, l16 = lane & 15;
    const int g    = blockIdx.x;
    const int bh   = (g & 7) + 8 * ((g >> 3) & 7);     // XCD = g%8 = bh%8
    const int qt   = 15 - (g >> 6);                    // [0,16), longest first
    const ushort_t* qptr = Q  + (long)bh * 2048 * 64;
    const ushort_t* kptr = K  + (long)bh * 2048 * 64;
    const ushort_t* vptr = Vt + (long)bh * 64 * 2048;
    const int bb2 = bh >> 4, h = bh & 15;

    const int srow = tid >> 3;
    const int slot = tid & 7;
    const int oct  = slot ^ (srow & 7);
    const int koff = srow * 64 + oct * 8;     // K elem offset (+ kt*4096); row1: +2048
    const int voff = srow * 2048 + oct * 8;   // V elem offset (+ kt*64);   row1: +65536
    const int wofs = srow * 64 + slot * 8;    // LDS write offset;          row1: +2048

    const int qbase = qt * 128;
    const int nkt = 2 * qt + 2;

    // all-ones bf16x8 for the l-row-sum MFMA (B[k][col] = 1)
    const u32x4 ones_u = {0x3F803F80u, 0x3F803F80u, 0x3F803F80u, 0x3F803F80u};
    const bf16x8 ones = __builtin_bit_cast(bf16x8, ones_u);

    // stage Q into Ps with XOR swizzle: P[row][col] at row*64 + (col^((row&7)*8))
    for (int c = 0; c < 4; ++c) {
        int flat = tid + 256 * c;
        int row = flat >> 3, kc = (flat & 7) * 8;
        *(u32x4*)&Ps[row * 64 + (kc ^ ((row & 7) * 8))] =
            *(const u32x4*)&qptr[(long)(qbase + row) * 64 + kc];
    }
    wg_barrier();
    bf16x8 qf[2][2];
    for (int nt = 0; nt < 2; ++nt)
        for (int kk = 0; kk < 2; ++kk) {
            int row = 32*w + 16*nt + l16;
            qf[nt][kk] = ldfrag(&Ps[row * 64 + ((kk*32 + quad*8) ^ ((row & 7) * 8))]);
        }

    f32x4 acc[2][4] = {};
    f32x4 accl[2]   = {};                              // l row-sums (MFMA pipe)

    auto phase = [&](int kt) {
        const int kbase = kt * 64;
        if (kbase > qbase + 32*w + 31) return;         // fully masked for wave
        // S^T = K.Q^T: rows = keys (16mt+4quad+r), cols = q (32w+16nt+l16)
        f32x4 s[4][2] = {};
        __builtin_amdgcn_s_setprio(1);
        for (int kk = 0; kk < 2; ++kk)
            for (int mt = 0; mt < 4; ++mt) {
                bf16x8 kf = ldfrag(&Ks[(16*mt + l16) * 64 + ((4*kk + quad) ^ (l16 & 7)) * 8]);
                for (int nt = 0; nt < 2; ++nt)
                    s[mt][nt] = mfma16(kf, qf[nt][kk], s[mt][nt]);
            }
        __builtin_amdgcn_s_setprio(0);
        if (kbase + 63 > qbase + 32*w) {               // straddles diagonal
            for (int mt = 0; mt < 4; ++mt)
                for (int nt = 0; nt < 2; ++nt) {
                    int qv = qbase + 32*w + 16*nt + l16;
                    for (int r = 0; r < 4; ++r)
                        if (kbase + 16*mt + 4*quad + r > qv)
                            s[mt][nt][r] = -__builtin_inff();
                }
        }
        // p = exp2(s) raw -> bf16 P fragments (swizzled P region)
        for (int nt = 0; nt < 2; ++nt) {
            int row = 32*w + 16*nt + l16;
            for (int mt = 0; mt < 4; ++mt) {
                float p0 = __builtin_amdgcn_exp2f(s[mt][nt][0]);
                float p1 = __builtin_amdgcn_exp2f(s[mt][nt][1]);
                float p2 = __builtin_amdgcn_exp2f(s[mt][nt][2]);
                float p3 = __builtin_amdgcn_exp2f(s[mt][nt][3]);
                u32x2 pk;
                pk.x = pack2bf_fast(p0, p1);
                pk.y = pack2bf_fast(p2, p3);
                *(u32x2*)&Ps[row * 64 + ((16*mt + 4*quad) ^ ((row & 7) * 8))] = pk;
            }
        }
        // O += P.V ; l += P.ones (same-wave DS write->read in order)
        __builtin_amdgcn_s_setprio(1);
        for (int kk = 0; kk < 2; ++kk) {
            int r0 = 32*w + l16, r1 = 32*w + 16 + l16;
            bf16x8 pf0 = ldfrag(&Ps[r0 * 64 + ((kk*32 + quad*8) ^ ((r0 & 7) * 8))]);
            bf16x8 pf1 = ldfrag(&Ps[r1 * 64 + ((kk*32 + quad*8) ^ ((r1 & 7) * 8))]);
            accl[0] = mfma16(pf0, ones, accl[0]);
            accl[1] = mfma16(pf1, ones, accl[1]);
            for (int jd = 0; jd < 4; ++jd) {
                bf16x8 vf = ldfrag(&Vs[(16*jd + l16) * 64 + ((4*kk + quad) ^ (l16 & 7)) * 8]);
                acc[0][jd] = mfma16(pf0, vf, acc[0][jd]);
                acc[1][jd] = mfma16(pf1, vf, acc[1][jd]);
            }
        }
        __builtin_amdgcn_s_setprio(0);
    };

    // single-set register prefetch, 1 tile ahead
    u32x4 K0 = *(const u32x4*)(kptr + koff);
    u32x4 K1 = *(const u32x4*)(kptr + koff + 2048);
    u32x4 V0 = *(const u32x4*)(vptr + voff);
    u32x4 V1 = *(const u32x4*)(vptr + voff + 65536);

    for (int kt = 0; kt < nkt; ++kt) {
        wg_barrier();                     // prev phase's LDS reads complete
        *(u32x4*)&Ks[wofs]        = K0;   // ds_write waits only these regs' loads
        *(u32x4*)&Ks[wofs + 2048] = K1;
        *(u32x4*)&Vs[wofs]        = V0;
        *(u32x4*)&Vs[wofs + 2048] = V1;
        int kf = (kt + 1 < nkt) ? kt + 1 : kt;
        K0 = *(const u32x4*)(kptr + kf*4096 + koff);
        K1 = *(const u32x4*)(kptr + kf*4096 + koff + 2048);
        V0 = *(const u32x4*)(vptr + kf*64 + voff);
        V1 = *(const u32x4*)(vptr + kf*64 + voff + 65536);
        wg_barrier();                     // K,V visible to all waves
        phase(kt);
    }

    // epilogue: l already per-lane in acc layout -- no shuffles.
    for (int i = 0; i < 2; ++i)
        for (int r = 0; r < 4; ++r) {
            float linv = 1.0f / accl[i][r];
            int t = qbase + 32*w + 16*i + 4*quad + r;
            for (int jd = 0; jd < 4; ++jd) {
                int d = 16*jd + l16;
                O[((long)(bb2*2048 + t)) * 1024 + h*64 + d] = f2bf(acc[i][jd][r] * linv);
            }
        }
}

// ---------------------------------------------------------------------------
// GEMM2: out = attn_out @ W_proj + b.  (round-2 proven pipeline: gld_lds
// 3-buffer rotation, counted vmcnt, one barrier per phase; fp32 epilogue)
// ---------------------------------------------------------------------------
__global__ __launch_bounds__(256) void gemm_proj(const ushort_t* __restrict__ A,
                                                 const ushort_t* __restrict__ Wt,
                                                 const float* __restrict__ bias,
                                                 float* __restrict__ Out) {
    __shared__ __align__(16) ushort_t smem[24576];

    const int tid  = threadIdx.x;
    const int g    = blockIdx.x;
    const int grp  = g / 64, rr = g % 64;
    const int m0   = (grp * 8 + (rr & 7)) * 128;
    const int n0   = (rr >> 3) * 128;
    const int lane = tid & 63, w = tid >> 6;
    const int quad = lane >> 4, l16 = lane & 15;
    const int wm = (w >> 1) * 64, wn = (w & 1) * 64;

    const int srow  = tid >> 2;
    const int slot  = tid & 3;
    const int oct   = slot ^ ((tid >> 3) & 3);
    const int rslot = (quad ^ ((l16 >> 1) & 3)) * 8;
    const int wbase = (tid & 192) * 8;

    const ushort_t* Ap = A  + (long)(m0 + srow) * 1024 + oct * 8;
    const ushort_t* Bp = Wt + (long)(n0 + srow) * 1024 + oct * 8;

    f32x4 acc[4][4] = {};

    auto issue = [&](int pf, int ibuf) {
        int k = (pf < 32) ? (pf << 5) : 0;
        gld16(Ap + k,         &smem[ibuf + wbase]);
        gld16(Ap + k + 65536, &smem[ibuf + wbase + 2048]);
        gld16(Bp + k,         &smem[ibuf + wbase + 4096]);
        gld16(Bp + k + 65536, &smem[ibuf + wbase + 6144]);
    };
    auto step = [&](int p, int rbuf, int ibuf) {
        asm volatile("s_waitcnt vmcnt(4)\n\ts_barrier" ::: "memory");
        issue(p + 2, ibuf);
        const ushort_t* As = smem + rbuf;
        const ushort_t* Bs = As + 4096;
        bf16x8 af[4], bfr[4];
        for (int i = 0; i < 4; ++i)
            af[i] = ldfrag(&As[(wm + 16*i + l16) * 32 + rslot]);
        for (int j = 0; j < 4; ++j)
            bfr[j] = ldfrag(&Bs[(wn + 16*j + l16) * 32 + rslot]);
        __builtin_amdgcn_s_setprio(1);
        for (int i = 0; i < 4; ++i)
            for (int j = 0; j < 4; ++j)
                acc[i][j] = mfma16(af[i], bfr[j], acc[i][j]);
        __builtin_amdgcn_s_setprio(0);
    };

    issue(0, 0);
    issue(1, 8192);
    for (int p = 0; p < 30; p += 3) {
        step(p,     0,     16384);
        step(p + 1, 8192,  0);
        step(p + 2, 16384, 8192);
    }
    step(30, 0,    16384);
    step(31, 8192, 0);
    asm volatile("s_waitcnt vmcnt(0)" ::: "memory");    // drain junk tail loads

    float bj[4];
    for (int j = 0; j < 4; ++j) bj[j] = bias[n0 + wn + 16*j + l16];
    for (int i = 0; i < 4; ++i)
        for (int j = 0; j < 4; ++j)
            for (int r = 0; r < 4; ++r) {
                int m = m0 + wm + 16*i + quad*4 + r;
                int n = n0 + wn + 16*j + l16;
                Out[(long)m * 1024 + n] = acc[i][j][r] + bj[j];
            }
}

// ---------------------------------------------------------------------------
extern "C" void kernel_launch(void* const* d_in, const int* in_sizes, int n_in,
                              void* d_out, int out_size, void* d_ws, size_t ws_size,
                              hipStream_t stream) {
    const float* x     = (const float*)d_in[0];
    const float* Wqkv  = (const float*)d_in[1];
    const float* bqkv  = (const float*)d_in[2];
    const float* Wproj = (const float*)d_in[3];
    const float* bproj = (const float*)d_in[4];
    float* out = (float*)d_out;

    // workspace carve-up (bf16 elements), total ~75.5 MB
    ushort_t* wqkvt  = (ushort_t*)d_ws;            // 3072*1024
    ushort_t* wprojt = wqkvt  + 3072 * 1024;       // 1024*1024
    ushort_t* Qb     = wprojt + 1024 * 1024;       // 8M  [B,H,T,D] (pre-scaled)
    ushort_t* Kb     = Qb  + 8388608;              // 8M  [B,H,T,D]
    ushort_t* Vtb    = Kb  + 8388608;              // 8M  [B,H,D,T]
    ushort_t* XbA2   = Vtb + 8388608;              // 8M  x-bf16, later attn out

    prep<<<8192, 256, 0, stream>>>(x, XbA2, Wqkv, wqkvt, Wproj, wprojt);
    gemm_qkv<<<1536, 256, 0, stream>>>(XbA2, wqkvt, bqkv, Qb, Kb, Vtb);
    attn_kernel<<<1024, 256, 0, stream>>>(Qb, Kb, Vtb, XbA2);
    gemm_proj<<<512, 256, 0, stream>>>(XbA2, wprojt, bproj, out);
}

// Round 10
// 240.694 us; speedup vs baseline: 1.1049x; 1.1049x over previous
//
#include <hip/hip_runtime.h>
#include <stdint.h>

typedef unsigned short ushort_t;
typedef __attribute__((ext_vector_type(4))) unsigned int  u32x4;
typedef __attribute__((ext_vector_type(2))) unsigned int  u32x2;
typedef __attribute__((ext_vector_type(4))) float         f32x4;
typedef __attribute__((ext_vector_type(8))) __bf16        bf16x8;
typedef __attribute__((ext_vector_type(2))) __bf16        bf16x2;

__device__ __forceinline__ ushort_t f2bf(float f) {
    unsigned int u = __float_as_uint(f);
    u += 0x7fffu + ((u >> 16) & 1u);
    return (ushort_t)(u >> 16);
}
__device__ __forceinline__ unsigned int pack2bf(float a, float b) {
    return (unsigned int)f2bf(a) | ((unsigned int)f2bf(b) << 16);
}
#if __has_builtin(__builtin_amdgcn_cvt_pk_bf16_f32)
__device__ __forceinline__ unsigned int pack2bf_fast(float a, float b) {
    bf16x2 v = __builtin_amdgcn_cvt_pk_bf16_f32(a, b);
    return __builtin_bit_cast(unsigned int, v);
}
#else
__device__ __forceinline__ unsigned int pack2bf_fast(float a, float b) {
    return pack2bf(a, b);
}
#endif
__device__ __forceinline__ f32x4 mfma16(bf16x8 a, bf16x8 b, f32x4 c) {
    return __builtin_amdgcn_mfma_f32_16x16x32_bf16(a, b, c, 0, 0, 0);
}
__device__ __forceinline__ bf16x8 ldfrag(const ushort_t* p) {
    return __builtin_bit_cast(bf16x8, *(const u32x4*)p);
}

// async global->LDS 16B: LDS dest = wave-uniform base + lane*16 (linear);
// swizzle lives in the per-lane GLOBAL source address (guide m97/m173).
__device__ __forceinline__ void gld16(const ushort_t* g, ushort_t* l) {
    __builtin_amdgcn_global_load_lds(
        (const __attribute__((address_space(1))) void*)g,
        (__attribute__((address_space(3))) void*)l, 16, 0, 0);
}

// Raw workgroup barrier WITHOUT the vmcnt(0) drain __syncthreads emits.
__device__ __forceinline__ void wg_barrier() {
    asm volatile("s_waitcnt lgkmcnt(0)\n\ts_barrier" ::: "memory");
}

// 0.125 (1/sqrt(64)) * log2(e): folded into Q so softmax uses exp2
#define QSCALE 0.18033688011112042f

// ---------------------------------------------------------------------------
// prep: fused  xcast (blocks 0..4095) | Wqkv^T (4096..7167) | Wproj^T (rest)
// ---------------------------------------------------------------------------
__global__ __launch_bounds__(256) void prep(const float* __restrict__ X,
                                            ushort_t* __restrict__ Xb,
                                            const float* __restrict__ Wq,
                                            ushort_t* __restrict__ Wqt,
                                            const float* __restrict__ Wp,
                                            ushort_t* __restrict__ Wpt) {
    __shared__ float tile[32][33];
    const int tid = threadIdx.x;
    const int b   = blockIdx.x;
    if (b < 4096) {                      // x fp32 -> bf16, 8 elems/thread
        long i = ((long)b * 256 + tid) * 8;
        float4 a = *(const float4*)(X + i);
        float4 c = *(const float4*)(X + i + 4);
        u32x4 pk;
        pk.x = pack2bf(a.x, a.y); pk.y = pack2bf(a.z, a.w);
        pk.z = pack2bf(c.x, c.y); pk.w = pack2bf(c.z, c.w);
        *(u32x4*)(Xb + i) = pk;
        return;
    }
    const float* W; ushort_t* Wt; int N, bx, by;
    if (b < 7168) { int idx = b - 4096; W = Wq; Wt = Wqt; N = 3072; bx = idx % 96; by = idx / 96; }
    else          { int idx = b - 7168; W = Wp; Wt = Wpt; N = 1024; bx = idx & 31; by = idx >> 5; }
    const int tx = tid & 31, ty = tid >> 5;
    const int n0 = bx * 32, k0 = by * 32;
    for (int p = 0; p < 4; ++p)
        tile[ty + 8*p][tx] = W[(long)(k0 + ty + 8*p) * N + n0 + tx];
    __syncthreads();
    for (int p = 0; p < 4; ++p)
        Wt[(long)(n0 + ty + 8*p) * 1024 + k0 + tx] = f2bf(tile[tx][ty + 8*p]);
}

// ---------------------------------------------------------------------------
// GEMM1: qkv = xb @ Wt + b.  (round-2 proven pipeline: gld_lds staging,
// 3-buffer rotation, ONE barrier per 32-wide K-phase with counted
// s_waitcnt vmcnt(4); prefetch never drained in-loop. 48KB LDS.)
// ---------------------------------------------------------------------------
__global__ __launch_bounds__(256) void gemm_qkv(const ushort_t* __restrict__ Xb,
                                                const ushort_t* __restrict__ Wt,
                                                const float* __restrict__ bias,
                                                ushort_t* __restrict__ Qo,
                                                ushort_t* __restrict__ Ko,
                                                ushort_t* __restrict__ Vto) {
    __shared__ __align__(16) ushort_t smem[24576];

    const int tid  = threadIdx.x;
    const int g    = blockIdx.x;
    const int grp  = g / 192, rr = g % 192;
    const int m0   = (grp * 8 + (rr & 7)) * 128;
    const int n0   = (rr >> 3) * 128;
    const int lane = tid & 63, w = tid >> 6;
    const int quad = lane >> 4, l16 = lane & 15;
    const int wm = (w >> 1) * 64, wn = (w & 1) * 64;

    const int srow  = tid >> 2;
    const int slot  = tid & 3;
    const int oct   = slot ^ ((tid >> 3) & 3);          // global-side swizzle
    const int rslot = (quad ^ ((l16 >> 1) & 3)) * 8;    // frag-read swizzled slot
    const int wbase = (tid & 192) * 8;                  // wave-uniform LDS base

    const ushort_t* Ap = Xb + (long)(m0 + srow) * 1024 + oct * 8;
    const ushort_t* Bp = Wt + (long)(n0 + srow) * 1024 + oct * 8;

    f32x4 acc[4][4] = {};

    auto issue = [&](int pf, int ibuf) {
        int k = (pf < 32) ? (pf << 5) : 0;              // clamp: harmless junk
        gld16(Ap + k,         &smem[ibuf + wbase]);
        gld16(Ap + k + 65536, &smem[ibuf + wbase + 2048]);
        gld16(Bp + k,         &smem[ibuf + wbase + 4096]);
        gld16(Bp + k + 65536, &smem[ibuf + wbase + 6144]);
    };
    auto step = [&](int p, int rbuf, int ibuf) {
        asm volatile("s_waitcnt vmcnt(4)\n\ts_barrier" ::: "memory");
        issue(p + 2, ibuf);
        const ushort_t* As = smem + rbuf;
        const ushort_t* Bs = As + 4096;
        bf16x8 af[4], bfr[4];
        for (int i = 0; i < 4; ++i)
            af[i] = ldfrag(&As[(wm + 16*i + l16) * 32 + rslot]);
        for (int j = 0; j < 4; ++j)
            bfr[j] = ldfrag(&Bs[(wn + 16*j + l16) * 32 + rslot]);
        __builtin_amdgcn_s_setprio(1);
        for (int i = 0; i < 4; ++i)
            for (int j = 0; j < 4; ++j)
                acc[i][j] = mfma16(af[i], bfr[j], acc[i][j]);
        __builtin_amdgcn_s_setprio(0);
    };

    issue(0, 0);
    issue(1, 8192);
    for (int p = 0; p < 30; p += 3) {
        step(p,     0,     16384);
        step(p + 1, 8192,  0);
        step(p + 2, 16384, 8192);
    }
    step(30, 0,    16384);
    step(31, 8192, 0);

    float bj[4];
    for (int j = 0; j < 4; ++j) bj[j] = bias[n0 + wn + 16*j + l16];
    const int bb = m0 >> 11, t0m = m0 & 2047;
    asm volatile("s_waitcnt vmcnt(0)" ::: "memory");    // junk tail loads landed
    __syncthreads();                                    // smem reuse safe

    if (n0 < 2048) {
        // Q or K: transpose-in-LDS as [t_local][n_local], store 16B chunks
        ushort_t* dst = (n0 < 1024) ? Qo : Ko;
        const float scale = (n0 < 1024) ? QSCALE : 1.0f;
        const int nbase = (n0 < 1024) ? n0 : n0 - 1024;
        for (int i = 0; i < 4; ++i)
            for (int j = 0; j < 4; ++j) {
                int nl = wn + 16*j + l16;
                for (int r = 0; r < 4; ++r) {
                    int ml = wm + 16*i + quad*4 + r;
                    smem[ml * 136 + nl] = f2bf((acc[i][j][r] + bj[j]) * scale);
                }
            }
        __syncthreads();
        for (int c = 0; c < 8; ++c) {
            int chunk = tid + 256 * c;
            int row = chunk >> 4, nc = (chunk & 15) * 8;
            int n = nbase + nc;
            int hh = n >> 6, d = n & 63;
            *(u32x4*)&dst[((long)(bb*16 + hh) * 2048 + t0m + row) * 64 + d] =
                *(const u32x4*)&smem[row * 136 + nc];
        }
    } else {
        // V: transpose as [n_local][t_local], store [B,H,D,T] 16B chunks
        for (int i = 0; i < 4; ++i)
            for (int j = 0; j < 4; ++j) {
                int nl = wn + 16*j + l16;
                for (int r = 0; r < 4; ++r) {
                    int ml = wm + 16*i + quad*4 + r;
                    smem[nl * 136 + ml] = f2bf(acc[i][j][r] + bj[j]);
                }
            }
        __syncthreads();
        for (int c = 0; c < 8; ++c) {
            int chunk = tid + 256 * c;
            int row = chunk >> 4, mc = (chunk & 15) * 8;
            int n = n0 - 2048 + row;
            int hh = n >> 6, d = n & 63;
            *(u32x4*)&Vto[((long)(bb*16 + hh) * 64 + d) * 2048 + t0m + mc] =
                *(const u32x4*)&smem[row * 136 + mc];
        }
    }
}

// ---------------------------------------------------------------------------
// Causal flash attention (R8-proven structure, restored verbatim): K AND V
// LDS-staged, parity double-buffer, register ping-pong prefetch 2 tiles
// ahead, ONE raw barrier per phase (the dbuf is what keeps the prefetch
// vmcnt wait OFF the all-waves critical path -- R9's single-buffer proved
// the 2-barrier window serializes it: 80us vs 65). Softmax denominator l
// on the MFMA pipe: accl[i] = mfma16(pf_i, ones, accl[i]) -- exact P-row
// sums in acc layout; epilogue is linv = 1/accl[i][r], no shuffles.
// ---------------------------------------------------------------------------
__global__ __launch_bounds__(256) void attn_kernel(const ushort_t* __restrict__ Q,
                                                   const ushort_t* __restrict__ K,
                                                   const ushort_t* __restrict__ Vt,
                                                   ushort_t* __restrict__ O) {
    __shared__ __align__(16) ushort_t Ks[2][64 * 64];  // parity dbuf, swizzled
    __shared__ __align__(16) ushort_t Vs[2][64 * 64];
    __shared__ __align__(16) ushort_t Ps[128 * 72];    // Q staging + P

    const int tid  = threadIdx.x;
    const int lane = tid & 63, w = tid >> 6, quad = lane >> 4, l16 = lane & 15;
    const int g    = blockIdx.x;
    const int bh   = (g & 7) + 8 * ((g >> 3) & 7);     // XCD = g%8 = bh%8
    const int qt   = 15 - (g >> 6);                    // [0,16), longest first
    const ushort_t* qptr = Q  + (long)bh * 2048 * 64;
    const ushort_t* kptr = K  + (long)bh * 2048 * 64;
    const ushort_t* vptr = Vt + (long)bh * 64 * 2048;
    const int bb2 = bh >> 4, h = bh & 15;

    const int srow = tid >> 3;
    const int slot = tid & 7;
    const int oct  = slot ^ (srow & 7);
    const int koff = srow * 64 + oct * 8;     // K elem offset (+ kt*4096); row1: +2048
    const int voff = srow * 2048 + oct * 8;   // V elem offset (+ kt*64);   row1: +65536
    const int wofs = srow * 64 + slot * 8;    // LDS write offset;          row1: +2048

    const int qbase = qt * 128;
    const int nkt = 2 * qt + 2;                        // always even

    // all-ones bf16x8 for the l-row-sum MFMA (B[k][col] = 1)
    const u32x4 ones_u = {0x3F803F80u, 0x3F803F80u, 0x3F803F80u, 0x3F803F80u};
    const bf16x8 ones = __builtin_bit_cast(bf16x8, ones_u);

    for (int c = 0; c < 4; ++c) {
        int flat = tid + 256 * c;
        int row = flat >> 3, kc = (flat & 7) * 8;
        *(u32x4*)&Ps[row * 72 + kc] = *(const u32x4*)&qptr[(long)(qbase + row) * 64 + kc];
    }
    wg_barrier();
    bf16x8 qf[2][2];
    for (int nt = 0; nt < 2; ++nt)
        for (int kk = 0; kk < 2; ++kk)
            qf[nt][kk] = ldfrag(&Ps[(32*w + 16*nt + l16) * 72 + kk*32 + quad*8]);

    f32x4 acc[2][4] = {};
    f32x4 accl[2]   = {};                              // l row-sums (MFMA pipe)

    auto phase = [&](int kt, ushort_t* Kb, ushort_t* Vb) {
        const int kbase = kt * 64;
        if (kbase > qbase + 32*w + 31) return;         // fully masked for wave
        // S^T = K.Q^T: rows = keys (16mt+4quad+r), cols = q (32w+16nt+l16)
        f32x4 s[4][2] = {};
        __builtin_amdgcn_s_setprio(1);
        for (int kk = 0; kk < 2; ++kk)
            for (int mt = 0; mt < 4; ++mt) {
                bf16x8 kf = ldfrag(&Kb[(16*mt + l16) * 64 + ((4*kk + quad) ^ (l16 & 7)) * 8]);
                for (int nt = 0; nt < 2; ++nt)
                    s[mt][nt] = mfma16(kf, qf[nt][kk], s[mt][nt]);
            }
        __builtin_amdgcn_s_setprio(0);
        if (kbase + 63 > qbase + 32*w) {               // straddles diagonal
            for (int mt = 0; mt < 4; ++mt)
                for (int nt = 0; nt < 2; ++nt) {
                    int qv = qbase + 32*w + 16*nt + l16;
                    for (int r = 0; r < 4; ++r)
                        if (kbase + 16*mt + 4*quad + r > qv)
                            s[mt][nt][r] = -__builtin_inff();
                }
        }
        // p = exp2(s) raw -> bf16 P fragments (no VALU l accumulation)
        for (int nt = 0; nt < 2; ++nt)
            for (int mt = 0; mt < 4; ++mt) {
                float p0 = __builtin_amdgcn_exp2f(s[mt][nt][0]);
                float p1 = __builtin_amdgcn_exp2f(s[mt][nt][1]);
                float p2 = __builtin_amdgcn_exp2f(s[mt][nt][2]);
                float p3 = __builtin_amdgcn_exp2f(s[mt][nt][3]);
                u32x2 pk;
                pk.x = pack2bf_fast(p0, p1);
                pk.y = pack2bf_fast(p2, p3);
                *(u32x2*)&Ps[(32*w + 16*nt + l16) * 72 + 16*mt + 4*quad] = pk;
            }
        // O += P.V ; l += P.ones (same-wave DS write->read in order)
        __builtin_amdgcn_s_setprio(1);
        for (int kk = 0; kk < 2; ++kk) {
            bf16x8 pf0 = ldfrag(&Ps[(32*w + l16) * 72 + kk*32 + quad*8]);
            bf16x8 pf1 = ldfrag(&Ps[(32*w + 16 + l16) * 72 + kk*32 + quad*8]);
            accl[0] = mfma16(pf0, ones, accl[0]);
            accl[1] = mfma16(pf1, ones, accl[1]);
            for (int jd = 0; jd < 4; ++jd) {
                bf16x8 vf = ldfrag(&Vb[(16*jd + l16) * 64 + ((4*kk + quad) ^ (l16 & 7)) * 8]);
                acc[0][jd] = mfma16(pf0, vf, acc[0][jd]);
                acc[1][jd] = mfma16(pf1, vf, acc[1][jd]);
            }
        }
        __builtin_amdgcn_s_setprio(0);
    };

    // ping-pong sets: A = even tiles, B = odd tiles
    u32x4 KA0 = *(const u32x4*)(kptr + koff);
    u32x4 KA1 = *(const u32x4*)(kptr + koff + 2048);
    u32x4 VA0 = *(const u32x4*)(vptr + voff);
    u32x4 VA1 = *(const u32x4*)(vptr + voff + 65536);
    u32x4 KB0 = *(const u32x4*)(kptr + 4096 + koff);
    u32x4 KB1 = *(const u32x4*)(kptr + 4096 + koff + 2048);
    u32x4 VB0 = *(const u32x4*)(vptr + 64 + voff);
    u32x4 VB1 = *(const u32x4*)(vptr + 64 + voff + 65536);

    for (int kt = 0; kt < nkt; kt += 2) {
        {   // phase A: tile kt, parity 0
            *(u32x4*)&Ks[0][wofs]        = KA0;        // waits only set-A loads
            *(u32x4*)&Ks[0][wofs + 2048] = KA1;
            *(u32x4*)&Vs[0][wofs]        = VA0;
            *(u32x4*)&Vs[0][wofs + 2048] = VA1;
            int kf = (kt + 2 < nkt) ? kt + 2 : kt;
            KA0 = *(const u32x4*)(kptr + kf*4096 + koff);
            KA1 = *(const u32x4*)(kptr + kf*4096 + koff + 2048);
            VA0 = *(const u32x4*)(vptr + kf*64 + voff);
            VA1 = *(const u32x4*)(vptr + kf*64 + voff + 65536);
            wg_barrier();
            phase(kt, Ks[0], Vs[0]);
        }
        {   // phase B: tile kt+1, parity 1
            *(u32x4*)&Ks[1][wofs]        = KB0;
            *(u32x4*)&Ks[1][wofs + 2048] = KB1;
            *(u32x4*)&Vs[1][wofs]        = VB0;
            *(u32x4*)&Vs[1][wofs + 2048] = VB1;
            int kf = (kt + 3 < nkt) ? kt + 3 : kt + 1;
            KB0 = *(const u32x4*)(kptr + kf*4096 + koff);
            KB1 = *(const u32x4*)(kptr + kf*4096 + koff + 2048);
            VB0 = *(const u32x4*)(vptr + kf*64 + voff);
            VB1 = *(const u32x4*)(vptr + kf*64 + voff + 65536);
            wg_barrier();
            phase(kt + 1, Ks[1], Vs[1]);
        }
    }

    // epilogue: l already per-lane in acc layout -- no shuffles.
    for (int i = 0; i < 2; ++i)
        for (int r = 0; r < 4; ++r) {
            float linv = 1.0f / accl[i][r];
            int t = qbase + 32*w + 16*i + 4*quad + r;
            for (int jd = 0; jd < 4; ++jd) {
                int d = 16*jd + l16;
                O[((long)(bb2*2048 + t)) * 1024 + h*64 + d] = f2bf(acc[i][jd][r] * linv);
            }
        }
}

// ---------------------------------------------------------------------------
// GEMM2: out = attn_out @ W_proj + b.  (round-2 proven pipeline: gld_lds
// 3-buffer rotation, counted vmcnt, one barrier per phase; fp32 epilogue)
// ---------------------------------------------------------------------------
__global__ __launch_bounds__(256) void gemm_proj(const ushort_t* __restrict__ A,
                                                 const ushort_t* __restrict__ Wt,
                                                 const float* __restrict__ bias,
                                                 float* __restrict__ Out) {
    __shared__ __align__(16) ushort_t smem[24576];

    const int tid  = threadIdx.x;
    const int g    = blockIdx.x;
    const int grp  = g / 64, rr = g % 64;
    const int m0   = (grp * 8 + (rr & 7)) * 128;
    const int n0   = (rr >> 3) * 128;
    const int lane = tid & 63, w = tid >> 6;
    const int quad = lane >> 4, l16 = lane & 15;
    const int wm = (w >> 1) * 64, wn = (w & 1) * 64;

    const int srow  = tid >> 2;
    const int slot  = tid & 3;
    const int oct   = slot ^ ((tid >> 3) & 3);
    const int rslot = (quad ^ ((l16 >> 1) & 3)) * 8;
    const int wbase = (tid & 192) * 8;

    const ushort_t* Ap = A  + (long)(m0 + srow) * 1024 + oct * 8;
    const ushort_t* Bp = Wt + (long)(n0 + srow) * 1024 + oct * 8;

    f32x4 acc[4][4] = {};

    auto issue = [&](int pf, int ibuf) {
        int k = (pf < 32) ? (pf << 5) : 0;
        gld16(Ap + k,         &smem[ibuf + wbase]);
        gld16(Ap + k + 65536, &smem[ibuf + wbase + 2048]);
        gld16(Bp + k,         &smem[ibuf + wbase + 4096]);
        gld16(Bp + k + 65536, &smem[ibuf + wbase + 6144]);
    };
    auto step = [&](int p, int rbuf, int ibuf) {
        asm volatile("s_waitcnt vmcnt(4)\n\ts_barrier" ::: "memory");
        issue(p + 2, ibuf);
        const ushort_t* As = smem + rbuf;
        const ushort_t* Bs = As + 4096;
        bf16x8 af[4], bfr[4];
        for (int i = 0; i < 4; ++i)
            af[i] = ldfrag(&As[(wm + 16*i + l16) * 32 + rslot]);
        for (int j = 0; j < 4; ++j)
            bfr[j] = ldfrag(&Bs[(wn + 16*j + l16) * 32 + rslot]);
        __builtin_amdgcn_s_setprio(1);
        for (int i = 0; i < 4; ++i)
            for (int j = 0; j < 4; ++j)
                acc[i][j] = mfma16(af[i], bfr[j], acc[i][j]);
        __builtin_amdgcn_s_setprio(0);
    };

    issue(0, 0);
    issue(1, 8192);
    for (int p = 0; p < 30; p += 3) {
        step(p,     0,     16384);
        step(p + 1, 8192,  0);
        step(p + 2, 16384, 8192);
    }
    step(30, 0,    16384);
    step(31, 8192, 0);
    asm volatile("s_waitcnt vmcnt(0)" ::: "memory");    // drain junk tail loads

    float bj[4];
    for (int j = 0; j < 4; ++j) bj[j] = bias[n0 + wn + 16*j + l16];
    for (int i = 0; i < 4; ++i)
        for (int j = 0; j < 4; ++j)
            for (int r = 0; r < 4; ++r) {
                int m = m0 + wm + 16*i + quad*4 + r;
                int n = n0 + wn + 16*j + l16;
                Out[(long)m * 1024 + n] = acc[i][j][r] + bj[j];
            }
}

// ---------------------------------------------------------------------------
extern "C" void kernel_launch(void* const* d_in, const int* in_sizes, int n_in,
                              void* d_out, int out_size, void* d_ws, size_t ws_size,
                              hipStream_t stream) {
    const float* x     = (const float*)d_in[0];
    const float* Wqkv  = (const float*)d_in[1];
    const float* bqkv  = (const float*)d_in[2];
    const float* Wproj = (const float*)d_in[3];
    const float* bproj = (const float*)d_in[4];
    float* out = (float*)d_out;

    // workspace carve-up (bf16 elements), total ~75.5 MB
    ushort_t* wqkvt  = (ushort_t*)d_ws;            // 3072*1024
    ushort_t* wprojt = wqkvt  + 3072 * 1024;       // 1024*1024
    ushort_t* Qb     = wprojt + 1024 * 1024;       // 8M  [B,H,T,D] (pre-scaled)
    ushort_t* Kb     = Qb  + 8388608;              // 8M  [B,H,T,D]
    ushort_t* Vtb    = Kb  + 8388608;              // 8M  [B,H,D,T]
    ushort_t* XbA2   = Vtb + 8388608;              // 8M  x-bf16, later attn out

    prep<<<8192, 256, 0, stream>>>(x, XbA2, Wqkv, wqkvt, Wproj, wprojt);
    gemm_qkv<<<1536, 256, 0, stream>>>(XbA2, wqkvt, bqkv, Qb, Kb, Vtb);
    attn_kernel<<<1024, 256, 0, stream>>>(Qb, Kb, Vtb, XbA2);
    gemm_proj<<<512, 256, 0, stream>>>(XbA2, wprojt, bproj, out);
}